// Round 4
// baseline (832.900 us; speedup 1.0000x reference)
//
#include <hip/hip_runtime.h>
#include <hip/hip_bf16.h>

#define EPS 1e-5f
#define DIMH 128
#define K1 320
#define K3 256

typedef __attribute__((ext_vector_type(8))) short bf16x8;
typedef __attribute__((ext_vector_type(4))) short bf16x4;
typedef __attribute__((ext_vector_type(4))) float f32x4;

#define MFMA(a, b, c) __builtin_amdgcn_mfma_f32_16x16x32_bf16(a, b, c, 0, 0, 0)

static __device__ __forceinline__ unsigned short f2bf(float f) {
    union { float f; unsigned u; } v; v.f = f;
    unsigned r = v.u + 0x7FFF + ((v.u >> 16) & 1);
    return (unsigned short)(r >> 16);
}

// ---------- weight prep: W1t [128][320], W4t [128][128], W3comb top half ----
__global__ void k_prep_w(const float* __restrict__ W1, const float* __restrict__ W3,
                         const float* __restrict__ W4,
                         unsigned short* __restrict__ W1t, unsigned short* __restrict__ W3c,
                         unsigned short* __restrict__ W4t) {
    int t = blockIdx.x * 256 + threadIdx.x;
    if (t < K1 * 128) { int k = t / 128, n = t % 128; W1t[n * K1 + k] = f2bf(W1[t]); }
    if (t < 128 * 128) {
        int k = t / 128, n = t % 128;
        W4t[n * 128 + k] = f2bf(W4[t]);
        W3c[n * K3 + k] = f2bf(W3[t]);          // top half: k<128 rows of W3
    }
}

// ---------- h -> bf16 ----------
__global__ void k_hb(const float* __restrict__ h, unsigned short* __restrict__ hb, int total8) {
    int t = blockIdx.x * 256 + threadIdx.x;
    if (t < total8) {
        float4 a = *(const float4*)(h + (size_t)t * 8);
        float4 b = *(const float4*)(h + (size_t)t * 8 + 4);
        union { bf16x8 v; unsigned short s[8]; } u;
        u.s[0] = f2bf(a.x); u.s[1] = f2bf(a.y); u.s[2] = f2bf(a.z); u.s[3] = f2bf(a.w);
        u.s[4] = f2bf(b.x); u.s[5] = f2bf(b.y); u.s[6] = f2bf(b.z); u.s[7] = f2bf(b.w);
        *(bf16x8*)(hb + (size_t)t * 8) = u.v;
    }
}

// ---------- P = W2 @ W3_bot  -> W3comb bottom half (transposed bf16) --------
__global__ void k_w23(const float* __restrict__ W2, const float* __restrict__ W3,
                      unsigned short* __restrict__ W3c) {
    int t = blockIdx.x * 256 + threadIdx.x;   // 16384 threads
    int j = t & 127, i = t >> 7;
    float s = 0.f;
    for (int k = 0; k < 128; ++k) s += W2[i * 128 + k] * W3[(128 + k) * 128 + j];
    W3c[j * K3 + 128 + i] = f2bf(s);
}

// ---------- cvec = b2 @ W3_bot ----------
__global__ void k_cvec(const float* __restrict__ b2, const float* __restrict__ W3,
                       float* __restrict__ cvec) {
    int j = threadIdx.x;
    float s = 0.f;
    for (int k = 0; k < 128; ++k) s += b2[k] * W3[(128 + k) * 128 + j];
    cvec[j] = s;
}

// ---------- BN params ----------
__global__ void k_bn(const float* __restrict__ stats, const float* __restrict__ g,
                     const float* __restrict__ be, float* __restrict__ st, float cnt) {
    int c = threadIdx.x;
    float mean = stats[c] / cnt;
    float var = stats[128 + c] / cnt - mean * mean;
    float s = g[c] * rsqrtf(var + EPS);
    st[c] = s;
    st[128 + c] = be[c] - mean * s;
}

// ---------- CSR build ----------
__global__ void k_deg(const int* __restrict__ dst, int* __restrict__ deg, int E) {
    int e = blockIdx.x * 256 + threadIdx.x;
    if (e < E) atomicAdd(&deg[dst[e]], 1);
}

__global__ void k_scan(const int* __restrict__ deg, int* __restrict__ offs,
                       int* __restrict__ cursor, int NN) {
    __shared__ int ps[1024];
    int t = threadIdx.x;
    int chunk = (NN + 1023) >> 10;
    int c0 = t * chunk;
    int s = 0;
    for (int i = 0; i < chunk; ++i) { int id = c0 + i; if (id < NN) s += deg[id]; }
    ps[t] = s; __syncthreads();
    for (int off = 1; off < 1024; off <<= 1) {
        int v = (t >= off) ? ps[t - off] : 0;
        __syncthreads();
        ps[t] += v;
        __syncthreads();
    }
    int run = t ? ps[t - 1] : 0;
    for (int i = 0; i < chunk; ++i) {
        int id = c0 + i;
        if (id < NN) { cursor[id] = run; run += deg[id]; offs[id] = run; }
    }
}

__global__ void k_scatter(const int* __restrict__ dst, int* __restrict__ cursor,
                          int* __restrict__ elist, int E) {
    int e = blockIdx.x * 256 + threadIdx.x;
    if (e < E) {
        int pos = atomicAdd(&cursor[dst[e]], 1);
        elist[pos] = e;
    }
}

// ---------- edge GEMM1: x = [hb_src|hb_dst|ea] @ W1 + b1, BN stats ----------
__global__ __launch_bounds__(256, 4) void k_msg1(
    const unsigned short* __restrict__ hb, const float* __restrict__ ea,
    const int* __restrict__ src, const int* __restrict__ dst,
    const unsigned short* __restrict__ W1t, const float* __restrict__ b1,
    unsigned short* __restrict__ xout, float* __restrict__ stats) {
    __shared__ unsigned short A[64 * K1];      // 40960 B -> 4 blocks/CU
    int tid = threadIdx.x, lane = tid & 63, w = tid >> 6;
    long e0 = (long)blockIdx.x * 64;

    bf16x8 bfr[10][2];
    {
        int n = (w << 5) + (lane & 15), kb = (lane >> 4) << 3;
#pragma unroll
        for (int nt = 0; nt < 2; ++nt) {
            const unsigned short* p = W1t + (size_t)(n + nt * 16) * K1 + kb;
#pragma unroll
            for (int ks = 0; ks < 10; ++ks) bfr[ks][nt] = *(const bf16x8*)(p + ks * 32);
        }
    }
    // stage: XOR-swizzled, bf16 copies for h parts, cvt for ea
    {
        int c16 = tid & 15, r2 = tid >> 4;
#pragma unroll
        for (int rr = 0; rr < 4; ++rr) {
            int row = rr * 16 + r2;
            long e = e0 + row;
            int s = src[e], d = dst[e];
            bf16x8 vs = *(const bf16x8*)(hb + (size_t)s * DIMH + c16 * 8);
            bf16x8 vd = *(const bf16x8*)(hb + (size_t)d * DIMH + c16 * 8);
            float4 ve = *(const float4*)(ea + (size_t)e * 64 + c16 * 4);
            int base = row * K1, sw = (row & 7) << 3;
            *(bf16x8*)&A[(base + c16 * 8) ^ sw] = vs;
            *(bf16x8*)&A[(base + 128 + c16 * 8) ^ sw] = vd;
            union { bf16x4 v4; unsigned short s4[4]; } u;
            u.s4[0] = f2bf(ve.x); u.s4[1] = f2bf(ve.y); u.s4[2] = f2bf(ve.z); u.s4[3] = f2bf(ve.w);
            *(bf16x4*)&A[(base + 256 + c16 * 4) ^ sw] = u.v4;
        }
    }
    __syncthreads();

    f32x4 acc[4][2] = {};
#pragma unroll
    for (int rg = 0; rg < 4; ++rg) {
        int arow = rg * 16 + (lane & 15);
        int base = arow * K1, sw = (arow & 7) << 3, kb = (lane >> 4) << 3;
#pragma unroll
        for (int ks = 0; ks < 10; ++ks) {
            bf16x8 af = *(const bf16x8*)&A[(base + ks * 32 + kb) ^ sw];
            acc[rg][0] = MFMA(af, bfr[ks][0], acc[rg][0]);
            acc[rg][1] = MFMA(af, bfr[ks][1], acc[rg][1]);
        }
    }
    int c0 = (w << 5) + (lane & 15);
    float bias0 = b1[c0], bias1 = b1[c0 + 16];
    float ss[2] = {0.f, 0.f}, sq[2] = {0.f, 0.f};
#pragma unroll
    for (int rg = 0; rg < 4; ++rg)
#pragma unroll
        for (int r = 0; r < 4; ++r) {
            long row = e0 + rg * 16 + ((lane >> 4) << 2) + r;
            float v0 = acc[rg][0][r] + bias0;
            float v1 = acc[rg][1][r] + bias1;
            ss[0] += v0; sq[0] += v0 * v0;
            ss[1] += v1; sq[1] += v1 * v1;
            xout[(size_t)row * DIMH + c0] = f2bf(v0);
            xout[(size_t)row * DIMH + c0 + 16] = f2bf(v1);
        }
#pragma unroll
    for (int nt = 0; nt < 2; ++nt) {
        ss[nt] += __shfl_xor(ss[nt], 16); ss[nt] += __shfl_xor(ss[nt], 32);
        sq[nt] += __shfl_xor(sq[nt], 16); sq[nt] += __shfl_xor(sq[nt], 32);
    }
    if (lane < 16) {
        atomicAdd(&stats[c0], ss[0]);        atomicAdd(&stats[c0 + 16], ss[1]);
        atomicAdd(&stats[128 + c0], sq[0]);  atomicAdd(&stats[128 + c0 + 16], sq[1]);
    }
}

// ---------- CSR gather-aggregate: R[n] = sum relu(bn(x_e)), no atomics ------
__global__ __launch_bounds__(256, 8) void k_agg(
    const unsigned short* __restrict__ x, const float* __restrict__ st,
    const int* __restrict__ offs, const int* __restrict__ deg,
    const int* __restrict__ elist, float* __restrict__ R, int NN) {
    int lane = threadIdx.x & 63, w = threadIdx.x >> 6;
    int n = blockIdx.x * 4 + w;
    if (n >= NN) return;
    int c = lane * 2;
    float s0 = st[c], s1 = st[c + 1], t0 = st[128 + c], t1 = st[128 + c + 1];
    int end = offs[n], start = end - deg[n];
    float a0 = 0.f, a1 = 0.f;
    int i = start;
    for (; i + 1 < end; i += 2) {
        int e0 = elist[i], e1 = elist[i + 1];
        unsigned v0 = *(const unsigned*)(x + (size_t)e0 * DIMH + c);
        unsigned v1 = *(const unsigned*)(x + (size_t)e1 * DIMH + c);
        float f;
        f = __uint_as_float(v0 << 16) * s0 + t0;         a0 += fmaxf(f, 0.f);
        f = __uint_as_float(v0 & 0xffff0000u) * s1 + t1; a1 += fmaxf(f, 0.f);
        f = __uint_as_float(v1 << 16) * s0 + t0;         a0 += fmaxf(f, 0.f);
        f = __uint_as_float(v1 & 0xffff0000u) * s1 + t1; a1 += fmaxf(f, 0.f);
    }
    if (i < end) {
        int e0 = elist[i];
        unsigned v0 = *(const unsigned*)(x + (size_t)e0 * DIMH + c);
        float f;
        f = __uint_as_float(v0 << 16) * s0 + t0;         a0 += fmaxf(f, 0.f);
        f = __uint_as_float(v0 & 0xffff0000u) * s1 + t1; a1 += fmaxf(f, 0.f);
    }
    *(float2*)(R + (size_t)n * DIMH + c) = make_float2(a0, a1);
}

// ---------- node GEMM: ypre = [hb|R] @ W3comb + b3 + deg*cvec, BN stats -----
__global__ __launch_bounds__(256, 4) void k_upd1(
    const unsigned short* __restrict__ hb, const float* __restrict__ R,
    const unsigned short* __restrict__ W3c, const float* __restrict__ b3,
    const int* __restrict__ deg, const float* __restrict__ cvec,
    unsigned short* __restrict__ ypre, float* __restrict__ stats, int NN) {
    __shared__ unsigned short A[64 * K3];      // 32768 B
    int tid = threadIdx.x, lane = tid & 63, w = tid >> 6;
    int n0 = blockIdx.x * 64;

    bf16x8 bfr[8][2];
    {
        int n = (w << 5) + (lane & 15), kb = (lane >> 4) << 3;
#pragma unroll
        for (int nt = 0; nt < 2; ++nt) {
            const unsigned short* p = W3c + (size_t)(n + nt * 16) * K3 + kb;
#pragma unroll
            for (int ks = 0; ks < 8; ++ks) bfr[ks][nt] = *(const bf16x8*)(p + ks * 32);
        }
    }
    {
        int c16 = tid & 15, r2 = tid >> 4;
#pragma unroll
        for (int rr = 0; rr < 4; ++rr) {
            int row = rr * 16 + r2;
            int node = n0 + row;
            bf16x8 vh = {};
            union { bf16x8 v8; unsigned short s8[8]; } ur;
            if (node < NN) {
                vh = *(const bf16x8*)(hb + (size_t)node * DIMH + c16 * 8);
                float4 r0 = *(const float4*)(R + (size_t)node * DIMH + c16 * 8);
                float4 r1 = *(const float4*)(R + (size_t)node * DIMH + c16 * 8 + 4);
                ur.s8[0] = f2bf(r0.x); ur.s8[1] = f2bf(r0.y); ur.s8[2] = f2bf(r0.z); ur.s8[3] = f2bf(r0.w);
                ur.s8[4] = f2bf(r1.x); ur.s8[5] = f2bf(r1.y); ur.s8[6] = f2bf(r1.z); ur.s8[7] = f2bf(r1.w);
            } else {
#pragma unroll
                for (int j = 0; j < 8; ++j) ur.s8[j] = 0;
            }
            int base = row * K3, sw = (row & 7) << 3;
            *(bf16x8*)&A[(base + c16 * 8) ^ sw] = vh;
            *(bf16x8*)&A[(base + 128 + c16 * 8) ^ sw] = ur.v8;
        }
    }
    __syncthreads();

    f32x4 acc[4][2] = {};
#pragma unroll
    for (int rg = 0; rg < 4; ++rg) {
        int arow = rg * 16 + (lane & 15);
        int base = arow * K3, sw = (arow & 7) << 3, kb = (lane >> 4) << 3;
#pragma unroll
        for (int ks = 0; ks < 8; ++ks) {
            bf16x8 af = *(const bf16x8*)&A[(base + ks * 32 + kb) ^ sw];
            acc[rg][0] = MFMA(af, bfr[ks][0], acc[rg][0]);
            acc[rg][1] = MFMA(af, bfr[ks][1], acc[rg][1]);
        }
    }
    int c0 = (w << 5) + (lane & 15);
    float bias0 = b3[c0], bias1 = b3[c0 + 16];
    float cv0 = cvec[c0], cv1 = cvec[c0 + 16];
    float ss[2] = {0.f, 0.f}, sq[2] = {0.f, 0.f};
#pragma unroll
    for (int rg = 0; rg < 4; ++rg)
#pragma unroll
        for (int r = 0; r < 4; ++r) {
            int node = n0 + rg * 16 + ((lane >> 4) << 2) + r;
            if (node < NN) {
                float dg = (float)deg[node];
                float v0 = acc[rg][0][r] + bias0 + dg * cv0;
                float v1 = acc[rg][1][r] + bias1 + dg * cv1;
                ss[0] += v0; sq[0] += v0 * v0;
                ss[1] += v1; sq[1] += v1 * v1;
                ypre[(size_t)node * DIMH + c0] = f2bf(v0);
                ypre[(size_t)node * DIMH + c0 + 16] = f2bf(v1);
            }
        }
#pragma unroll
    for (int nt = 0; nt < 2; ++nt) {
        ss[nt] += __shfl_xor(ss[nt], 16); ss[nt] += __shfl_xor(ss[nt], 32);
        sq[nt] += __shfl_xor(sq[nt], 16); sq[nt] += __shfl_xor(sq[nt], 32);
    }
    if (lane < 16) {
        atomicAdd(&stats[c0], ss[0]);        atomicAdd(&stats[c0 + 16], ss[1]);
        atomicAdd(&stats[128 + c0], sq[0]);  atomicAdd(&stats[128 + c0 + 16], sq[1]);
    }
}

// ---------- node GEMM2 + residual + LayerNorm ----------
__global__ __launch_bounds__(256, 2) void k_upd2(
    const unsigned short* __restrict__ ypre, const unsigned short* __restrict__ W4t,
    const float* __restrict__ b4, const float* __restrict__ st,
    const float* __restrict__ h, const float* __restrict__ lng,
    const float* __restrict__ lnb, float* __restrict__ out, int NN) {
    const int LDA = 136;
    __shared__ unsigned short A[64 * 136];
    __shared__ float sS[128], sT[128];
    __shared__ float rsum[64], rsq[64];
    int tid = threadIdx.x, lane = tid & 63, w = tid >> 6;
    int n0 = blockIdx.x * 64;
    if (tid < 128) { sS[tid] = st[tid]; sT[tid] = st[128 + tid]; }
    if (tid < 64) { rsum[tid] = 0.f; rsq[tid] = 0.f; }

    bf16x8 bfr[4][2];
    {
        int n = (w << 5) + (lane & 15), kb = (lane >> 4) << 3;
#pragma unroll
        for (int nt = 0; nt < 2; ++nt) {
            const unsigned short* p = W4t + (size_t)(n + nt * 16) * 128 + kb;
#pragma unroll
            for (int ks = 0; ks < 4; ++ks) bfr[ks][nt] = *(const bf16x8*)(p + ks * 32);
        }
    }
    __syncthreads();
    {
        int c16 = tid & 15, r2 = tid >> 4;
#pragma unroll
        for (int rr = 0; rr < 4; ++rr) {
            int row = rr * 16 + r2;
            int node = n0 + row;
            union { bf16x8 v8; unsigned short s[8]; } u;
            if (node < NN) {
                bf16x8 v = *(const bf16x8*)(ypre + (size_t)node * DIMH + c16 * 8);
#pragma unroll
                for (int j = 0; j < 8; ++j) {
                    int c = c16 * 8 + j;
                    union { unsigned uu; float f; } cvt; cvt.uu = ((unsigned)(unsigned short)v[j]) << 16;
                    float f = cvt.f * sS[c] + sT[c];
                    u.s[j] = f2bf(fmaxf(f, 0.f));
                }
            } else {
#pragma unroll
                for (int j = 0; j < 8; ++j) u.s[j] = 0;
            }
            *(bf16x8*)&A[row * LDA + c16 * 8] = u.v8;
        }
    }
    __syncthreads();

    f32x4 acc[4][2] = {};
#pragma unroll
    for (int rg = 0; rg < 4; ++rg) {
        int ab = (rg * 16 + (lane & 15)) * LDA + ((lane >> 4) << 3);
#pragma unroll
        for (int ks = 0; ks < 4; ++ks) {
            bf16x8 af = *(const bf16x8*)&A[ab + ks * 32];
            acc[rg][0] = MFMA(af, bfr[ks][0], acc[rg][0]);
            acc[rg][1] = MFMA(af, bfr[ks][1], acc[rg][1]);
        }
    }
    int c0 = (w << 5) + (lane & 15);
    float bias0 = b4[c0], bias1 = b4[c0 + 16];
    float z[4][2][4];
#pragma unroll
    for (int rg = 0; rg < 4; ++rg)
#pragma unroll
        for (int r = 0; r < 4; ++r) {
            int node = n0 + rg * 16 + ((lane >> 4) << 2) + r;
            float h0 = 0.f, h1 = 0.f;
            if (node < NN) {
                h0 = h[(size_t)node * DIMH + c0];
                h1 = h[(size_t)node * DIMH + c0 + 16];
            }
            z[rg][0][r] = acc[rg][0][r] + bias0 + h0;
            z[rg][1][r] = acc[rg][1][r] + bias1 + h1;
        }
#pragma unroll
    for (int rg = 0; rg < 4; ++rg)
#pragma unroll
        for (int r = 0; r < 4; ++r) {
            float ps = z[rg][0][r] + z[rg][1][r];
            float pq = z[rg][0][r] * z[rg][0][r] + z[rg][1][r] * z[rg][1][r];
#pragma unroll
            for (int m = 1; m < 16; m <<= 1) { ps += __shfl_xor(ps, m); pq += __shfl_xor(pq, m); }
            if ((lane & 15) == 0) {
                int row = rg * 16 + ((lane >> 4) << 2) + r;
                atomicAdd(&rsum[row], ps);
                atomicAdd(&rsq[row], pq);
            }
        }
    __syncthreads();
#pragma unroll
    for (int rg = 0; rg < 4; ++rg)
#pragma unroll
        for (int r = 0; r < 4; ++r) {
            int row = rg * 16 + ((lane >> 4) << 2) + r;
            int node = n0 + row;
            if (node < NN) {
                float mean = rsum[row] * (1.f / 128.f);
                float var = rsq[row] * (1.f / 128.f) - mean * mean;
                float rs = rsqrtf(var + EPS);
                float g0 = lng[c0], g1 = lng[c0 + 16];
                float be0 = lnb[c0], be1 = lnb[c0 + 16];
                out[(size_t)node * DIMH + c0] = (z[rg][0][r] - mean) * rs * g0 + be0;
                out[(size_t)node * DIMH + c0 + 16] = (z[rg][1][r] - mean) * rs * g1 + be1;
            }
        }
}

extern "C" void kernel_launch(void* const* d_in, const int* in_sizes, int n_in,
                              void* d_out, int out_size, void* d_ws, size_t ws_size,
                              hipStream_t stream) {
    const float* h   = (const float*)d_in[0];
    const float* ea  = (const float*)d_in[1];
    const float* W1  = (const float*)d_in[2];
    const float* b1  = (const float*)d_in[3];
    const float* g1  = (const float*)d_in[4];
    const float* be1 = (const float*)d_in[5];
    const float* W2  = (const float*)d_in[6];
    const float* b2  = (const float*)d_in[7];
    const float* W3  = (const float*)d_in[8];
    const float* b3  = (const float*)d_in[9];
    const float* g2  = (const float*)d_in[10];
    const float* be2 = (const float*)d_in[11];
    const float* W4  = (const float*)d_in[12];
    const float* b4  = (const float*)d_in[13];
    const float* lng = (const float*)d_in[14];
    const float* lnb = (const float*)d_in[15];
    const int* eidx  = (const int*)d_in[16];
    int NN = in_sizes[0] / DIMH;
    int E  = in_sizes[16] / 2;
    const int* src = eidx;
    const int* dst = eidx + E;

    char* ws = (char*)d_ws;
    size_t o = 0;
    unsigned short* W1t = (unsigned short*)(ws + o); o += 81920;
    unsigned short* W3c = (unsigned short*)(ws + o); o += 65536;
    unsigned short* W4t = (unsigned short*)(ws + o); o += 32768;
    float* cvec   = (float*)(ws + o); o += 512;
    float* stats1 = (float*)(ws + o); o += 1024;
    float* st1    = (float*)(ws + o); o += 1024;
    float* stats2 = (float*)(ws + o); o += 1024;
    float* st2    = (float*)(ws + o); o += 1024;
    int* deg    = (int*)(ws + o); o += 200192;
    int* offs   = (int*)(ws + o); o += 200192;
    int* cursor = (int*)(ws + o); o += 200192;
    int* elist  = (int*)(ws + o); o += (size_t)E * 4;
    unsigned short* hb = (unsigned short*)(ws + o); o += (size_t)NN * DIMH * 2;
    float* R = (float*)(ws + o); o += (size_t)NN * DIMH * 4;
    unsigned short* x = (unsigned short*)(ws + o);   // E*128*2
    unsigned short* ypre = x;                        // x dead after k_agg; reuse

    hipMemsetAsync(stats1, 0, 1024, stream);
    hipMemsetAsync(stats2, 0, 1024, stream);
    hipMemsetAsync(deg, 0, (size_t)NN * 4, stream);

    k_prep_w<<<(K1 * 128 + 255) / 256, 256, 0, stream>>>(W1, W3, W4, W1t, W3c, W4t);
    k_hb<<<(NN * DIMH / 8 + 255) / 256, 256, 0, stream>>>(h, hb, NN * DIMH / 8);
    k_w23<<<64, 256, 0, stream>>>(W2, W3, W3c);
    k_cvec<<<1, 128, 0, stream>>>(b2, W3, cvec);
    k_deg<<<(E + 255) / 256, 256, 0, stream>>>(dst, deg, E);
    k_scan<<<1, 1024, 0, stream>>>(deg, offs, cursor, NN);
    k_scatter<<<(E + 255) / 256, 256, 0, stream>>>(dst, cursor, elist, E);

    k_msg1<<<E / 64, 256, 0, stream>>>(hb, ea, src, dst, W1t, b1, x, stats1);
    k_bn<<<1, 128, 0, stream>>>(stats1, g1, be1, st1, (float)E);
    k_agg<<<(NN + 3) / 4, 256, 0, stream>>>(x, st1, offs, deg, elist, R, NN);

    int nb = (NN + 63) / 64;
    k_upd1<<<nb, 256, 0, stream>>>(hb, R, W3c, b3, deg, cvec, ypre, stats2, NN);
    k_bn<<<1, 128, 0, stream>>>(stats2, g2, be2, st2, (float)NN);
    k_upd2<<<nb, 256, 0, stream>>>(ypre, W4t, b4, st2, h, lng, lnb, (float*)d_out, NN);
}

// Round 5
// 812.587 us; speedup vs baseline: 1.0250x; 1.0250x over previous
//
#include <hip/hip_runtime.h>
#include <hip/hip_bf16.h>

#define EPS 1e-5f
#define DIMH 128
#define K1 320
#define K3 256

typedef __attribute__((ext_vector_type(8))) short bf16x8;
typedef __attribute__((ext_vector_type(4))) short bf16x4;
typedef __attribute__((ext_vector_type(4))) float f32x4;

#define MFMA(a, b, c) __builtin_amdgcn_mfma_f32_16x16x32_bf16(a, b, c, 0, 0, 0)

static __device__ __forceinline__ unsigned short f2bf(float f) {
    union { float f; unsigned u; } v; v.f = f;
    unsigned r = v.u + 0x7FFF + ((v.u >> 16) & 1);
    return (unsigned short)(r >> 16);
}

// async global->LDS, 16B per lane, wave-uniform LDS base
static __device__ __forceinline__ void gload16(const void* g, void* l) {
    __builtin_amdgcn_global_load_lds(
        (const __attribute__((address_space(1))) unsigned int*)g,
        (__attribute__((address_space(3))) unsigned int*)l, 16, 0, 0);
}

// ---------- weight prep: W1t [128][320], W4t [128][128], W3comb top half ----
__global__ void k_prep_w(const float* __restrict__ W1, const float* __restrict__ W3,
                         const float* __restrict__ W4,
                         unsigned short* __restrict__ W1t, unsigned short* __restrict__ W3c,
                         unsigned short* __restrict__ W4t) {
    int t = blockIdx.x * 256 + threadIdx.x;
    if (t < K1 * 128) { int k = t / 128, n = t % 128; W1t[n * K1 + k] = f2bf(W1[t]); }
    if (t < 128 * 128) {
        int k = t / 128, n = t % 128;
        W4t[n * 128 + k] = f2bf(W4[t]);
        W3c[n * K3 + k] = f2bf(W3[t]);          // top half: k<128 rows of W3
    }
}

// ---------- h -> bf16 ----------
__global__ void k_hb(const float* __restrict__ h, unsigned short* __restrict__ hb, int total8) {
    int t = blockIdx.x * 256 + threadIdx.x;
    if (t < total8) {
        float4 a = *(const float4*)(h + (size_t)t * 8);
        float4 b = *(const float4*)(h + (size_t)t * 8 + 4);
        union { bf16x8 v; unsigned short s[8]; } u;
        u.s[0] = f2bf(a.x); u.s[1] = f2bf(a.y); u.s[2] = f2bf(a.z); u.s[3] = f2bf(a.w);
        u.s[4] = f2bf(b.x); u.s[5] = f2bf(b.y); u.s[6] = f2bf(b.z); u.s[7] = f2bf(b.w);
        *(bf16x8*)(hb + (size_t)t * 8) = u.v;
    }
}

// ---------- P = W2 @ W3_bot  -> W3comb bottom half (transposed bf16) --------
__global__ void k_w23(const float* __restrict__ W2, const float* __restrict__ W3,
                      unsigned short* __restrict__ W3c) {
    int t = blockIdx.x * 256 + threadIdx.x;   // 16384 threads
    int j = t & 127, i = t >> 7;
    float s = 0.f;
    for (int k = 0; k < 128; ++k) s += W2[i * 128 + k] * W3[(128 + k) * 128 + j];
    W3c[j * K3 + 128 + i] = f2bf(s);
}

// ---------- cvec = b2 @ W3_bot ----------
__global__ void k_cvec(const float* __restrict__ b2, const float* __restrict__ W3,
                       float* __restrict__ cvec) {
    int j = threadIdx.x;
    float s = 0.f;
    for (int k = 0; k < 128; ++k) s += b2[k] * W3[(128 + k) * 128 + j];
    cvec[j] = s;
}

// ---------- BN params ----------
__global__ void k_bn(const float* __restrict__ stats, const float* __restrict__ g,
                     const float* __restrict__ be, float* __restrict__ st, float cnt) {
    int c = threadIdx.x;
    float mean = stats[c] / cnt;
    float var = stats[128 + c] / cnt - mean * mean;
    float s = g[c] * rsqrtf(var + EPS);
    st[c] = s;
    st[128 + c] = be[c] - mean * s;
}

// ---------- CSR build ----------
__global__ void k_deg(const int* __restrict__ dst, int* __restrict__ deg, int E) {
    int e = blockIdx.x * 256 + threadIdx.x;
    if (e < E) atomicAdd(&deg[dst[e]], 1);
}

__global__ void k_scan(const int* __restrict__ deg, int* __restrict__ offs,
                       int* __restrict__ cursor, int NN) {
    __shared__ int ps[1024];
    int t = threadIdx.x;
    int chunk = (NN + 1023) >> 10;
    int c0 = t * chunk;
    int s = 0;
    for (int i = 0; i < chunk; ++i) { int id = c0 + i; if (id < NN) s += deg[id]; }
    ps[t] = s; __syncthreads();
    for (int off = 1; off < 1024; off <<= 1) {
        int v = (t >= off) ? ps[t - off] : 0;
        __syncthreads();
        ps[t] += v;
        __syncthreads();
    }
    int run = t ? ps[t - 1] : 0;
    for (int i = 0; i < chunk; ++i) {
        int id = c0 + i;
        if (id < NN) { cursor[id] = run; run += deg[id]; offs[id] = run; }
    }
}

__global__ void k_scatter(const int* __restrict__ dst, int* __restrict__ cursor,
                          int* __restrict__ elist, int E) {
    int e = blockIdx.x * 256 + threadIdx.x;
    if (e < E) {
        int pos = atomicAdd(&cursor[dst[e]], 1);
        elist[pos] = e;
    }
}

// ---------- edge GEMM1: x = [hb_src|hb_dst|ea] @ W1 + b1, BN stats ----------
// Staging: global_load_lds (linear LDS dest) + pre-swizzled global source;
// ds_read applies the same XOR (rule: both-sides-or-neither).
__global__ __launch_bounds__(256, 3) void k_msg1(
    const unsigned short* __restrict__ hb, const float* __restrict__ ea,
    const int* __restrict__ src, const int* __restrict__ dst,
    const unsigned short* __restrict__ W1t, const float* __restrict__ b1,
    unsigned short* __restrict__ xout, float* __restrict__ stats) {
    __shared__ unsigned short As[64 * 128];   // 16 KB  (h_src part, k 0..127)
    __shared__ unsigned short Ad[64 * 128];   // 16 KB  (h_dst part, k 128..255)
    __shared__ unsigned short Ae[64 * 64];    //  8 KB  (edge_attr, k 256..319)
    int tid = threadIdx.x, lane = tid & 63, w = tid >> 6;
    int l15 = lane & 15, kq = lane >> 4;
    long e0 = (long)blockIdx.x * 64;

    // B fragments (W1t) resident in regs: 10 ksteps x 2 ntiles = 80 VGPR
    bf16x8 bfr[10][2];
    {
        int n = (w << 5) + l15, kb = kq << 3;
#pragma unroll
        for (int nt = 0; nt < 2; ++nt) {
            const unsigned short* p = W1t + (size_t)(n + nt * 16) * K1 + kb;
#pragma unroll
            for (int ks = 0; ks < 10; ++ks) bfr[ks][nt] = *(const bf16x8*)(p + ks * 32);
        }
    }
    // --- stage h_src / h_dst via global_load_lds (4 x 1KB each per wave) ---
    {
#pragma unroll
        for (int j = 0; j < 4; ++j) {
            int r4 = (w << 4) + j * 4;             // wave-uniform base row
            int row = r4 + kq;                     // this lane's row
            int u = l15 ^ (row & 7);               // inverse-swizzled source slot
            long e = e0 + row;
            int sI = src[e], dI = dst[e];
            gload16(hb + (size_t)sI * 128 + u * 8, &As[r4 * 128]);
            gload16(hb + (size_t)dI * 128 + u * 8, &Ad[r4 * 128]);
        }
    }
    // --- stage edge_attr: fp32 -> bf16 through regs, swizzled ds_write ---
    {
        int s8 = lane & 7, rq8 = lane >> 3;
#pragma unroll
        for (int p = 0; p < 2; ++p) {
            int row = (w << 4) + p * 8 + rq8;
            int u = (s8 ^ (row & 7)) << 3;         // element offset in ea row
            const float* ep = ea + (size_t)(e0 + row) * 64 + u;
            float4 va = *(const float4*)ep;
            float4 vb = *(const float4*)(ep + 4);
            union { bf16x8 v; unsigned short s[8]; } uu;
            uu.s[0] = f2bf(va.x); uu.s[1] = f2bf(va.y); uu.s[2] = f2bf(va.z); uu.s[3] = f2bf(va.w);
            uu.s[4] = f2bf(vb.x); uu.s[5] = f2bf(vb.y); uu.s[6] = f2bf(vb.z); uu.s[7] = f2bf(vb.w);
            *(bf16x8*)&Ae[row * 64 + s8 * 8] = uu.v;
        }
    }
    __syncthreads();

    f32x4 acc[4][2] = {};
#pragma unroll
    for (int rg = 0; rg < 4; ++rg) {
        int a = rg * 16 + l15;
        int swz = a & 7;
        const unsigned short* pAs = As + a * 128;
        const unsigned short* pAd = Ad + a * 128;
        const unsigned short* pAe = Ae + a * 64;
#pragma unroll
        for (int ks = 0; ks < 4; ++ks) {
            bf16x8 af = *(const bf16x8*)(pAs + (((ks << 2) + kq) ^ swz) * 8);
            acc[rg][0] = MFMA(af, bfr[ks][0], acc[rg][0]);
            acc[rg][1] = MFMA(af, bfr[ks][1], acc[rg][1]);
        }
#pragma unroll
        for (int ks = 0; ks < 4; ++ks) {
            bf16x8 af = *(const bf16x8*)(pAd + (((ks << 2) + kq) ^ swz) * 8);
            acc[rg][0] = MFMA(af, bfr[4 + ks][0], acc[rg][0]);
            acc[rg][1] = MFMA(af, bfr[4 + ks][1], acc[rg][1]);
        }
#pragma unroll
        for (int ks = 0; ks < 2; ++ks) {
            bf16x8 af = *(const bf16x8*)(pAe + (((ks << 2) + kq) ^ swz) * 8);
            acc[rg][0] = MFMA(af, bfr[8 + ks][0], acc[rg][0]);
            acc[rg][1] = MFMA(af, bfr[8 + ks][1], acc[rg][1]);
        }
    }
    // --- epilogue: +b1, BN stats, pack tile in LDS, coalesced dwordx4 out ---
    __syncthreads();                       // A reads complete; reuse As as xtile
    unsigned short* xt = As;               // 64x128 bf16 = 16 KB
    int c0 = (w << 5) + l15;
    float bias0 = b1[c0], bias1 = b1[c0 + 16];
    float ss0 = 0.f, ss1 = 0.f, sq0 = 0.f, sq1 = 0.f;
#pragma unroll
    for (int rg = 0; rg < 4; ++rg)
#pragma unroll
        for (int r = 0; r < 4; ++r) {
            int row = rg * 16 + (kq << 2) + r;
            float v0 = acc[rg][0][r] + bias0;
            float v1 = acc[rg][1][r] + bias1;
            ss0 += v0; sq0 += v0 * v0;
            ss1 += v1; sq1 += v1 * v1;
            xt[row * 128 + c0] = f2bf(v0);
            xt[row * 128 + c0 + 16] = f2bf(v1);
        }
    __syncthreads();
#pragma unroll
    for (int p = 0; p < 4; ++p) {
        int off8 = p * 2048 + tid * 8;
        *(bf16x8*)(xout + (size_t)e0 * 128 + off8) = *(const bf16x8*)(xt + off8);
    }
    ss0 += __shfl_xor(ss0, 16); ss0 += __shfl_xor(ss0, 32);
    sq0 += __shfl_xor(sq0, 16); sq0 += __shfl_xor(sq0, 32);
    ss1 += __shfl_xor(ss1, 16); ss1 += __shfl_xor(ss1, 32);
    sq1 += __shfl_xor(sq1, 16); sq1 += __shfl_xor(sq1, 32);
    if (lane < 16) {
        atomicAdd(&stats[c0], ss0);        atomicAdd(&stats[c0 + 16], ss1);
        atomicAdd(&stats[128 + c0], sq0);  atomicAdd(&stats[128 + c0 + 16], sq1);
    }
}

// ---------- CSR gather-aggregate: R[n] = sum relu(bn(x_e)), no atomics ------
__global__ __launch_bounds__(256, 8) void k_agg(
    const unsigned short* __restrict__ x, const float* __restrict__ st,
    const int* __restrict__ offs, const int* __restrict__ deg,
    const int* __restrict__ elist, float* __restrict__ R, int NN) {
    int lane = threadIdx.x & 63, w = threadIdx.x >> 6;
    int n = blockIdx.x * 4 + w;
    if (n >= NN) return;
    int c = lane * 2;
    float s0 = st[c], s1 = st[c + 1], t0 = st[128 + c], t1 = st[128 + c + 1];
    int end = offs[n], i = end - deg[n];
    float a0 = 0.f, a1 = 0.f;
    for (; i + 3 < end; i += 4) {
        int e0 = elist[i], e1 = elist[i + 1], e2 = elist[i + 2], e3 = elist[i + 3];
        unsigned v0 = *(const unsigned*)(x + (size_t)e0 * DIMH + c);
        unsigned v1 = *(const unsigned*)(x + (size_t)e1 * DIMH + c);
        unsigned v2 = *(const unsigned*)(x + (size_t)e2 * DIMH + c);
        unsigned v3 = *(const unsigned*)(x + (size_t)e3 * DIMH + c);
        a0 += fmaxf(__uint_as_float(v0 << 16) * s0 + t0, 0.f);
        a1 += fmaxf(__uint_as_float(v0 & 0xffff0000u) * s1 + t1, 0.f);
        a0 += fmaxf(__uint_as_float(v1 << 16) * s0 + t0, 0.f);
        a1 += fmaxf(__uint_as_float(v1 & 0xffff0000u) * s1 + t1, 0.f);
        a0 += fmaxf(__uint_as_float(v2 << 16) * s0 + t0, 0.f);
        a1 += fmaxf(__uint_as_float(v2 & 0xffff0000u) * s1 + t1, 0.f);
        a0 += fmaxf(__uint_as_float(v3 << 16) * s0 + t0, 0.f);
        a1 += fmaxf(__uint_as_float(v3 & 0xffff0000u) * s1 + t1, 0.f);
    }
    for (; i < end; ++i) {
        int e0 = elist[i];
        unsigned v0 = *(const unsigned*)(x + (size_t)e0 * DIMH + c);
        a0 += fmaxf(__uint_as_float(v0 << 16) * s0 + t0, 0.f);
        a1 += fmaxf(__uint_as_float(v0 & 0xffff0000u) * s1 + t1, 0.f);
    }
    *(float2*)(R + (size_t)n * DIMH + c) = make_float2(a0, a1);
}

// ---------- node GEMM: ypre = [hb|R] @ W3comb + b3 + deg*cvec, BN stats -----
__global__ __launch_bounds__(256, 3) void k_upd1(
    const unsigned short* __restrict__ hb, const float* __restrict__ R,
    const unsigned short* __restrict__ W3c, const float* __restrict__ b3,
    const int* __restrict__ deg, const float* __restrict__ cvec,
    unsigned short* __restrict__ ypre, float* __restrict__ stats, int NN) {
    __shared__ unsigned short A[64 * K3];      // 32768 B
    int tid = threadIdx.x, lane = tid & 63, w = tid >> 6;
    int n0 = blockIdx.x * 64;

    bf16x8 bfr[8][2];
    {
        int n = (w << 5) + (lane & 15), kb = (lane >> 4) << 3;
#pragma unroll
        for (int nt = 0; nt < 2; ++nt) {
            const unsigned short* p = W3c + (size_t)(n + nt * 16) * K3 + kb;
#pragma unroll
            for (int ks = 0; ks < 8; ++ks) bfr[ks][nt] = *(const bf16x8*)(p + ks * 32);
        }
    }
    {
        int c16 = tid & 15, r2 = tid >> 4;
#pragma unroll
        for (int rr = 0; rr < 4; ++rr) {
            int row = rr * 16 + r2;
            int node = n0 + row;
            bf16x8 vh = {};
            union { bf16x8 v8; unsigned short s8[8]; } ur;
            if (node < NN) {
                vh = *(const bf16x8*)(hb + (size_t)node * DIMH + c16 * 8);
                float4 r0 = *(const float4*)(R + (size_t)node * DIMH + c16 * 8);
                float4 r1 = *(const float4*)(R + (size_t)node * DIMH + c16 * 8 + 4);
                ur.s8[0] = f2bf(r0.x); ur.s8[1] = f2bf(r0.y); ur.s8[2] = f2bf(r0.z); ur.s8[3] = f2bf(r0.w);
                ur.s8[4] = f2bf(r1.x); ur.s8[5] = f2bf(r1.y); ur.s8[6] = f2bf(r1.z); ur.s8[7] = f2bf(r1.w);
            } else {
#pragma unroll
                for (int j = 0; j < 8; ++j) ur.s8[j] = 0;
            }
            int base = row * K3, sw = (row & 7) << 3;
            *(bf16x8*)&A[(base + c16 * 8) ^ sw] = vh;
            *(bf16x8*)&A[(base + 128 + c16 * 8) ^ sw] = ur.v8;
        }
    }
    __syncthreads();

    f32x4 acc[4][2] = {};
#pragma unroll
    for (int rg = 0; rg < 4; ++rg) {
        int arow = rg * 16 + (lane & 15);
        int base = arow * K3, sw = (arow & 7) << 3, kb = (lane >> 4) << 3;
#pragma unroll
        for (int ks = 0; ks < 8; ++ks) {
            bf16x8 af = *(const bf16x8*)&A[(base + ks * 32 + kb) ^ sw];
            acc[rg][0] = MFMA(af, bfr[ks][0], acc[rg][0]);
            acc[rg][1] = MFMA(af, bfr[ks][1], acc[rg][1]);
        }
    }
    int c0 = (w << 5) + (lane & 15);
    float bias0 = b3[c0], bias1 = b3[c0 + 16];
    float cv0 = cvec[c0], cv1 = cvec[c0 + 16];
    float ss[2] = {0.f, 0.f}, sq[2] = {0.f, 0.f};
#pragma unroll
    for (int rg = 0; rg < 4; ++rg)
#pragma unroll
        for (int r = 0; r < 4; ++r) {
            int node = n0 + rg * 16 + ((lane >> 4) << 2) + r;
            if (node < NN) {
                float dg = (float)deg[node];
                float v0 = acc[rg][0][r] + bias0 + dg * cv0;
                float v1 = acc[rg][1][r] + bias1 + dg * cv1;
                ss[0] += v0; sq[0] += v0 * v0;
                ss[1] += v1; sq[1] += v1 * v1;
                ypre[(size_t)node * DIMH + c0] = f2bf(v0);
                ypre[(size_t)node * DIMH + c0 + 16] = f2bf(v1);
            }
        }
#pragma unroll
    for (int nt = 0; nt < 2; ++nt) {
        ss[nt] += __shfl_xor(ss[nt], 16); ss[nt] += __shfl_xor(ss[nt], 32);
        sq[nt] += __shfl_xor(sq[nt], 16); sq[nt] += __shfl_xor(sq[nt], 32);
    }
    if (lane < 16) {
        atomicAdd(&stats[c0], ss[0]);        atomicAdd(&stats[c0 + 16], ss[1]);
        atomicAdd(&stats[128 + c0], sq[0]);  atomicAdd(&stats[128 + c0 + 16], sq[1]);
    }
}

// ---------- node GEMM2 + residual + LayerNorm ----------
__global__ __launch_bounds__(256, 2) void k_upd2(
    const unsigned short* __restrict__ ypre, const unsigned short* __restrict__ W4t,
    const float* __restrict__ b4, const float* __restrict__ st,
    const float* __restrict__ h, const float* __restrict__ lng,
    const float* __restrict__ lnb, float* __restrict__ out, int NN) {
    const int LDA = 136;
    __shared__ unsigned short A[64 * 136];
    __shared__ float sS[128], sT[128];
    __shared__ float rsum[64], rsq[64];
    int tid = threadIdx.x, lane = tid & 63, w = tid >> 6;
    int n0 = blockIdx.x * 64;
    if (tid < 128) { sS[tid] = st[tid]; sT[tid] = st[128 + tid]; }
    if (tid < 64) { rsum[tid] = 0.f; rsq[tid] = 0.f; }

    bf16x8 bfr[4][2];
    {
        int n = (w << 5) + (lane & 15), kb = (lane >> 4) << 3;
#pragma unroll
        for (int nt = 0; nt < 2; ++nt) {
            const unsigned short* p = W4t + (size_t)(n + nt * 16) * 128 + kb;
#pragma unroll
            for (int ks = 0; ks < 4; ++ks) bfr[ks][nt] = *(const bf16x8*)(p + ks * 32);
        }
    }
    __syncthreads();
    {
        int c16 = tid & 15, r2 = tid >> 4;
#pragma unroll
        for (int rr = 0; rr < 4; ++rr) {
            int row = rr * 16 + r2;
            int node = n0 + row;
            union { bf16x8 v8; unsigned short s[8]; } u;
            if (node < NN) {
                bf16x8 v = *(const bf16x8*)(ypre + (size_t)node * DIMH + c16 * 8);
#pragma unroll
                for (int j = 0; j < 8; ++j) {
                    int c = c16 * 8 + j;
                    union { unsigned uu; float f; } cvt; cvt.uu = ((unsigned)(unsigned short)v[j]) << 16;
                    float f = cvt.f * sS[c] + sT[c];
                    u.s[j] = f2bf(fmaxf(f, 0.f));
                }
            } else {
#pragma unroll
                for (int j = 0; j < 8; ++j) u.s[j] = 0;
            }
            *(bf16x8*)&A[row * LDA + c16 * 8] = u.v8;
        }
    }
    __syncthreads();

    f32x4 acc[4][2] = {};
#pragma unroll
    for (int rg = 0; rg < 4; ++rg) {
        int ab = (rg * 16 + (lane & 15)) * LDA + ((lane >> 4) << 3);
#pragma unroll
        for (int ks = 0; ks < 4; ++ks) {
            bf16x8 af = *(const bf16x8*)&A[ab + ks * 32];
            acc[rg][0] = MFMA(af, bfr[ks][0], acc[rg][0]);
            acc[rg][1] = MFMA(af, bfr[ks][1], acc[rg][1]);
        }
    }
    int c0 = (w << 5) + (lane & 15);
    float bias0 = b4[c0], bias1 = b4[c0 + 16];
    float z[4][2][4];
#pragma unroll
    for (int rg = 0; rg < 4; ++rg)
#pragma unroll
        for (int r = 0; r < 4; ++r) {
            int node = n0 + rg * 16 + ((lane >> 4) << 2) + r;
            float h0 = 0.f, h1 = 0.f;
            if (node < NN) {
                h0 = h[(size_t)node * DIMH + c0];
                h1 = h[(size_t)node * DIMH + c0 + 16];
            }
            z[rg][0][r] = acc[rg][0][r] + bias0 + h0;
            z[rg][1][r] = acc[rg][1][r] + bias1 + h1;
        }
#pragma unroll
    for (int rg = 0; rg < 4; ++rg)
#pragma unroll
        for (int r = 0; r < 4; ++r) {
            float ps = z[rg][0][r] + z[rg][1][r];
            float pq = z[rg][0][r] * z[rg][0][r] + z[rg][1][r] * z[rg][1][r];
#pragma unroll
            for (int m = 1; m < 16; m <<= 1) { ps += __shfl_xor(ps, m); pq += __shfl_xor(pq, m); }
            if ((lane & 15) == 0) {
                int row = rg * 16 + ((lane >> 4) << 2) + r;
                atomicAdd(&rsum[row], ps);
                atomicAdd(&rsq[row], pq);
            }
        }
    __syncthreads();
#pragma unroll
    for (int rg = 0; rg < 4; ++rg)
#pragma unroll
        for (int r = 0; r < 4; ++r) {
            int row = rg * 16 + ((lane >> 4) << 2) + r;
            int node = n0 + row;
            if (node < NN) {
                float mean = rsum[row] * (1.f / 128.f);
                float var = rsq[row] * (1.f / 128.f) - mean * mean;
                float rs = rsqrtf(var + EPS);
                float g0 = lng[c0], g1 = lng[c0 + 16];
                float be0 = lnb[c0], be1 = lnb[c0 + 16];
                out[(size_t)node * DIMH + c0] = (z[rg][0][r] - mean) * rs * g0 + be0;
                out[(size_t)node * DIMH + c0 + 16] = (z[rg][1][r] - mean) * rs * g1 + be1;
            }
        }
}

extern "C" void kernel_launch(void* const* d_in, const int* in_sizes, int n_in,
                              void* d_out, int out_size, void* d_ws, size_t ws_size,
                              hipStream_t stream) {
    const float* h   = (const float*)d_in[0];
    const float* ea  = (const float*)d_in[1];
    const float* W1  = (const float*)d_in[2];
    const float* b1  = (const float*)d_in[3];
    const float* g1  = (const float*)d_in[4];
    const float* be1 = (const float*)d_in[5];
    const float* W2  = (const float*)d_in[6];
    const float* b2  = (const float*)d_in[7];
    const float* W3  = (const float*)d_in[8];
    const float* b3  = (const float*)d_in[9];
    const float* g2  = (const float*)d_in[10];
    const float* be2 = (const float*)d_in[11];
    const float* W4  = (const float*)d_in[12];
    const float* b4  = (const float*)d_in[13];
    const float* lng = (const float*)d_in[14];
    const float* lnb = (const float*)d_in[15];
    const int* eidx  = (const int*)d_in[16];
    int NN = in_sizes[0] / DIMH;
    int E  = in_sizes[16] / 2;
    const int* src = eidx;
    const int* dst = eidx + E;

    char* ws = (char*)d_ws;
    size_t o = 0;
    unsigned short* W1t = (unsigned short*)(ws + o); o += 81920;
    unsigned short* W3c = (unsigned short*)(ws + o); o += 65536;
    unsigned short* W4t = (unsigned short*)(ws + o); o += 32768;
    float* cvec   = (float*)(ws + o); o += 512;
    float* stats1 = (float*)(ws + o); o += 1024;
    float* st1    = (float*)(ws + o); o += 1024;
    float* stats2 = (float*)(ws + o); o += 1024;
    float* st2    = (float*)(ws + o); o += 1024;
    int* deg    = (int*)(ws + o); o += 200192;
    int* offs   = (int*)(ws + o); o += 200192;
    int* cursor = (int*)(ws + o); o += 200192;
    int* elist  = (int*)(ws + o); o += (size_t)E * 4;
    unsigned short* hb = (unsigned short*)(ws + o); o += (size_t)NN * DIMH * 2;
    float* R = (float*)(ws + o); o += (size_t)NN * DIMH * 4;
    unsigned short* x = (unsigned short*)(ws + o);   // E*128*2
    unsigned short* ypre = x;                        // x dead after k_agg; reuse

    hipMemsetAsync(stats1, 0, 1024, stream);
    hipMemsetAsync(stats2, 0, 1024, stream);
    hipMemsetAsync(deg, 0, (size_t)NN * 4, stream);

    k_prep_w<<<(K1 * 128 + 255) / 256, 256, 0, stream>>>(W1, W3, W4, W1t, W3c, W4t);
    k_hb<<<(NN * DIMH / 8 + 255) / 256, 256, 0, stream>>>(h, hb, NN * DIMH / 8);
    k_w23<<<64, 256, 0, stream>>>(W2, W3, W3c);
    k_cvec<<<1, 128, 0, stream>>>(b2, W3, cvec);
    k_deg<<<(E + 255) / 256, 256, 0, stream>>>(dst, deg, E);
    k_scan<<<1, 1024, 0, stream>>>(deg, offs, cursor, NN);
    k_scatter<<<(E + 255) / 256, 256, 0, stream>>>(dst, cursor, elist, E);

    k_msg1<<<E / 64, 256, 0, stream>>>(hb, ea, src, dst, W1t, b1, x, stats1);
    k_bn<<<1, 128, 0, stream>>>(stats1, g1, be1, st1, (float)E);
    k_agg<<<(NN + 3) / 4, 256, 0, stream>>>(x, st1, offs, deg, elist, R, NN);

    int nb = (NN + 63) / 64;
    k_upd1<<<nb, 256, 0, stream>>>(hb, R, W3c, b3, deg, cvec, ypre, stats2, NN);
    k_bn<<<1, 128, 0, stream>>>(stats2, g2, be2, st2, (float)NN);
    k_upd2<<<nb, 256, 0, stream>>>(ypre, W4t, b4, st2, h, lng, lnb, (float*)d_out, NN);
}

// Round 8
// 709.067 us; speedup vs baseline: 1.1746x; 1.1460x over previous
//
#include <hip/hip_runtime.h>
#include <hip/hip_bf16.h>

#define EPS 1e-5f
#define DIMH 128
#define K1 320
#define K3 256

typedef __attribute__((ext_vector_type(8))) short bf16x8;
typedef __attribute__((ext_vector_type(4))) short bf16x4;
typedef __attribute__((ext_vector_type(4))) float f32x4;

#define MFMA(a, b, c) __builtin_amdgcn_mfma_f32_16x16x32_bf16(a, b, c, 0, 0, 0)

static __device__ __forceinline__ unsigned short f2bf(float f) {
    union { float f; unsigned u; } v; v.f = f;
    unsigned r = v.u + 0x7FFF + ((v.u >> 16) & 1);
    return (unsigned short)(r >> 16);
}

// async global->LDS, 16B per lane, wave-uniform LDS base
static __device__ __forceinline__ void gload16(const void* g, void* l) {
    __builtin_amdgcn_global_load_lds(
        (const __attribute__((address_space(1))) unsigned int*)g,
        (__attribute__((address_space(3))) unsigned int*)l, 16, 0, 0);
}

// ---------- weight prep ----------
__global__ void k_prep_w(const float* __restrict__ W1, const float* __restrict__ W3,
                         const float* __restrict__ W4,
                         unsigned short* __restrict__ W1t, unsigned short* __restrict__ W3c,
                         unsigned short* __restrict__ W4t) {
    int t = blockIdx.x * 256 + threadIdx.x;
    if (t < K1 * 128) { int k = t / 128, n = t % 128; W1t[n * K1 + k] = f2bf(W1[t]); }
    if (t < 128 * 128) {
        int k = t / 128, n = t % 128;
        W4t[n * 128 + k] = f2bf(W4[t]);
        W3c[n * K3 + k] = f2bf(W3[t]);
    }
}

// ---------- h -> bf16 ----------
__global__ void k_hb(const float* __restrict__ h, unsigned short* __restrict__ hb, int total8) {
    int t = blockIdx.x * 256 + threadIdx.x;
    if (t < total8) {
        float4 a = *(const float4*)(h + (size_t)t * 8);
        float4 b = *(const float4*)(h + (size_t)t * 8 + 4);
        union { bf16x8 v; unsigned short s[8]; } u;
        u.s[0] = f2bf(a.x); u.s[1] = f2bf(a.y); u.s[2] = f2bf(a.z); u.s[3] = f2bf(a.w);
        u.s[4] = f2bf(b.x); u.s[5] = f2bf(b.y); u.s[6] = f2bf(b.z); u.s[7] = f2bf(b.w);
        *(bf16x8*)(hb + (size_t)t * 8) = u.v;
    }
}

// ---------- P = W2 @ W3_bot ----------
__global__ void k_w23(const float* __restrict__ W2, const float* __restrict__ W3,
                      unsigned short* __restrict__ W3c) {
    int t = blockIdx.x * 256 + threadIdx.x;
    int j = t & 127, i = t >> 7;
    float s = 0.f;
    for (int k = 0; k < 128; ++k) s += W2[i * 128 + k] * W3[(128 + k) * 128 + j];
    W3c[j * K3 + 128 + i] = f2bf(s);
}

// ---------- cvec = b2 @ W3_bot ----------
__global__ void k_cvec(const float* __restrict__ b2, const float* __restrict__ W3,
                       float* __restrict__ cvec) {
    int j = threadIdx.x;
    float s = 0.f;
    for (int k = 0; k < 128; ++k) s += b2[k] * W3[(128 + k) * 128 + j];
    cvec[j] = s;
}

// ---------- BN params ----------
__global__ void k_bn(const float* __restrict__ stats, const float* __restrict__ g,
                     const float* __restrict__ be, float* __restrict__ st, float cnt) {
    int c = threadIdx.x;
    float mean = stats[c] / cnt;
    float var = stats[128 + c] / cnt - mean * mean;
    float s = g[c] * rsqrtf(var + EPS);
    st[c] = s;
    st[128 + c] = be[c] - mean * s;
}

// ---------- CSR build ----------
__global__ void k_deg(const int* __restrict__ dst, int* __restrict__ deg, int E) {
    int e = blockIdx.x * 256 + threadIdx.x;
    if (e < E) atomicAdd(&deg[dst[e]], 1);
}

// parallel scan: block partial sums -> scan of sums -> per-block offsets
__global__ void k_part(const int* __restrict__ deg, int* __restrict__ bsum, int NN) {
    __shared__ int s[256];
    int t = threadIdx.x, g = blockIdx.x * 256 + t;
    s[t] = (g < NN) ? deg[g] : 0;
    __syncthreads();
    for (int o = 128; o > 0; o >>= 1) { if (t < o) s[t] += s[t + o]; __syncthreads(); }
    if (t == 0) bsum[blockIdx.x] = s[0];
}

__global__ void k_scan2(const int* __restrict__ bsum, int* __restrict__ bpre, int nb) {
    __shared__ int s[256];
    int t = threadIdx.x;
    int v = (t < nb) ? bsum[t] : 0;
    s[t] = v; __syncthreads();
    for (int o = 1; o < 256; o <<= 1) {
        int u = (t >= o) ? s[t - o] : 0;
        __syncthreads();
        s[t] += u;
        __syncthreads();
    }
    if (t < nb) bpre[t] = s[t] - v;   // exclusive prefix of block sums
}

__global__ void k_off(const int* __restrict__ deg, const int* __restrict__ bpre,
                      int* __restrict__ offs, int* __restrict__ cursor, int NN) {
    __shared__ int s[256];
    int t = threadIdx.x, g = blockIdx.x * 256 + t;
    int v = (g < NN) ? deg[g] : 0;
    s[t] = v; __syncthreads();
    for (int o = 1; o < 256; o <<= 1) {
        int u = (t >= o) ? s[t - o] : 0;
        __syncthreads();
        s[t] += u;
        __syncthreads();
    }
    if (g < NN) {
        int incl = s[t] + bpre[blockIdx.x];
        offs[g] = incl;          // inclusive end
        cursor[g] = incl - v;    // exclusive start
    }
}

// scatter: emit dst-sorted edge table {src, dst, edge_id}
__global__ void k_scatter(const int* __restrict__ src, const int* __restrict__ dst,
                          int* __restrict__ cursor, int4* __restrict__ edge4, int E) {
    int e = blockIdx.x * 256 + threadIdx.x;
    if (e < E) {
        int d = dst[e];
        int pos = atomicAdd(&cursor[d], 1);
        edge4[pos] = make_int4(src[e], d, e, 0);
    }
}

// ---------- edge GEMM1 (dst-sorted): x[p] = [hb_s|hb_d|ea] @ W1 + b1 --------
#define QSTEP(PTR, FIDX, BA, BB) do { \
    bf16x8 af = *(const bf16x8*)((PTR) + ((((FIDX)) ^ swz) << 3)); \
    acc[rg][0] = MFMA(af, BA, acc[rg][0]); \
    acc[rg][1] = MFMA(af, BB, acc[rg][1]); } while (0)

__global__ __launch_bounds__(256)
__attribute__((amdgpu_waves_per_eu(2, 3)))
void k_msg1(const unsigned short* __restrict__ hb, const float* __restrict__ ea,
            const int4* __restrict__ edge4, const unsigned short* __restrict__ W1t,
            const float* __restrict__ b1, unsigned short* __restrict__ xout,
            float* __restrict__ stats) {
    __shared__ unsigned short As[64 * 128];   // 16 KB  (h_src, k 0..127)
    __shared__ unsigned short Ad[64 * 128];   // 16 KB  (h_dst, k 128..255)
    __shared__ unsigned short Ae[64 * 64];    //  8 KB  (edge_attr, k 256..319)
    int tid = threadIdx.x, lane = tid & 63, w = tid >> 6;
    int l15 = lane & 15, kq = lane >> 4;
    long e0 = (long)blockIdx.x * 64;          // sorted position base

    // B fragments: 20 named 16B values, pinned resident (80 VGPRs)
    bf16x8 B0a, B1a, B2a, B3a, B4a, B5a, B6a, B7a, B8a, B9a;
    bf16x8 B0b, B1b, B2b, B3b, B4b, B5b, B6b, B7b, B8b, B9b;
    {
        int n = (w << 5) + l15, kb = kq << 3;
        const unsigned short* p0 = W1t + (size_t)n * K1 + kb;
        const unsigned short* p1 = p0 + 16 * K1;
        B0a = *(const bf16x8*)(p0 + 0);   B0b = *(const bf16x8*)(p1 + 0);
        B1a = *(const bf16x8*)(p0 + 32);  B1b = *(const bf16x8*)(p1 + 32);
        B2a = *(const bf16x8*)(p0 + 64);  B2b = *(const bf16x8*)(p1 + 64);
        B3a = *(const bf16x8*)(p0 + 96);  B3b = *(const bf16x8*)(p1 + 96);
        B4a = *(const bf16x8*)(p0 + 128); B4b = *(const bf16x8*)(p1 + 128);
        B5a = *(const bf16x8*)(p0 + 160); B5b = *(const bf16x8*)(p1 + 160);
        B6a = *(const bf16x8*)(p0 + 192); B6b = *(const bf16x8*)(p1 + 192);
        B7a = *(const bf16x8*)(p0 + 224); B7b = *(const bf16x8*)(p1 + 224);
        B8a = *(const bf16x8*)(p0 + 256); B8b = *(const bf16x8*)(p1 + 256);
        B9a = *(const bf16x8*)(p0 + 288); B9b = *(const bf16x8*)(p1 + 288);
    }
    asm volatile("" : "+v"(B0a), "+v"(B1a), "+v"(B2a), "+v"(B3a), "+v"(B4a),
                      "+v"(B5a), "+v"(B6a), "+v"(B7a), "+v"(B8a), "+v"(B9a));
    asm volatile("" : "+v"(B0b), "+v"(B1b), "+v"(B2b), "+v"(B3b), "+v"(B4b),
                      "+v"(B5b), "+v"(B6b), "+v"(B7b), "+v"(B8b), "+v"(B9b));

    // --- stage h_src / h_dst via global_load_lds (pre-swizzled source) ---
#pragma unroll
    for (int j = 0; j < 4; ++j) {
        int r4 = (w << 4) + j * 4;
        int row = r4 + kq;
        int4 ei = edge4[e0 + row];
        int u = l15 ^ (row & 7);
        gload16(hb + (size_t)ei.x * 128 + u * 8, &As[r4 * 128]);
        gload16(hb + (size_t)ei.y * 128 + u * 8, &Ad[r4 * 128]);
    }
    // --- stage edge_attr: fp32 -> bf16 through regs, swizzled write ---
    {
        int s8 = lane & 7, rq8 = lane >> 3;
#pragma unroll
        for (int p = 0; p < 2; ++p) {
            int row = (w << 4) + p * 8 + rq8;
            int eid = edge4[e0 + row].z;
            int u = (s8 ^ (row & 7)) << 3;
            const float* ep = ea + (size_t)eid * 64 + u;
            float4 va = *(const float4*)ep;
            float4 vb = *(const float4*)(ep + 4);
            union { bf16x8 v; unsigned short s[8]; } uu;
            uu.s[0] = f2bf(va.x); uu.s[1] = f2bf(va.y); uu.s[2] = f2bf(va.z); uu.s[3] = f2bf(va.w);
            uu.s[4] = f2bf(vb.x); uu.s[5] = f2bf(vb.y); uu.s[6] = f2bf(vb.z); uu.s[7] = f2bf(vb.w);
            *(bf16x8*)&Ae[row * 64 + s8 * 8] = uu.v;
        }
    }
    __syncthreads();

    f32x4 acc[4][2] = {};
#pragma unroll
    for (int rg = 0; rg < 4; ++rg) {
        int a = rg * 16 + l15;
        int swz = a & 7;
        const unsigned short* pAs = As + a * 128;
        const unsigned short* pAd = Ad + a * 128;
        const unsigned short* pAe = Ae + a * 64;
        QSTEP(pAs, (0 << 2) + kq, B0a, B0b);
        QSTEP(pAs, (1 << 2) + kq, B1a, B1b);
        QSTEP(pAs, (2 << 2) + kq, B2a, B2b);
        QSTEP(pAs, (3 << 2) + kq, B3a, B3b);
        QSTEP(pAd, (0 << 2) + kq, B4a, B4b);
        QSTEP(pAd, (1 << 2) + kq, B5a, B5b);
        QSTEP(pAd, (2 << 2) + kq, B6a, B6b);
        QSTEP(pAd, (3 << 2) + kq, B7a, B7b);
        QSTEP(pAe, (0 << 2) + kq, B8a, B8b);
        QSTEP(pAe, (1 << 2) + kq, B9a, B9b);
    }
    // --- epilogue: +b1, BN stats, pack tile in LDS, coalesced stores ---
    __syncthreads();
    unsigned short* xt = As;
    int c0 = (w << 5) + l15;
    float bias0 = b1[c0], bias1 = b1[c0 + 16];
    float ss0 = 0.f, ss1 = 0.f, sq0 = 0.f, sq1 = 0.f;
#pragma unroll
    for (int rg = 0; rg < 4; ++rg)
#pragma unroll
        for (int r = 0; r < 4; ++r) {
            int row = rg * 16 + (kq << 2) + r;
            float v0 = acc[rg][0][r] + bias0;
            float v1 = acc[rg][1][r] + bias1;
            ss0 += v0; sq0 += v0 * v0;
            ss1 += v1; sq1 += v1 * v1;
            xt[row * 128 + c0] = f2bf(v0);
            xt[row * 128 + c0 + 16] = f2bf(v1);
        }
    __syncthreads();
#pragma unroll
    for (int p = 0; p < 4; ++p) {
        int off8 = p * 2048 + tid * 8;
        *(bf16x8*)(xout + (size_t)e0 * 128 + off8) = *(const bf16x8*)(xt + off8);
    }
    ss0 += __shfl_xor(ss0, 16); ss0 += __shfl_xor(ss0, 32);
    sq0 += __shfl_xor(sq0, 16); sq0 += __shfl_xor(sq0, 32);
    ss1 += __shfl_xor(ss1, 16); ss1 += __shfl_xor(ss1, 32);
    sq1 += __shfl_xor(sq1, 16); sq1 += __shfl_xor(sq1, 32);
    if (lane < 16) {
        atomicAdd(&stats[c0], ss0);        atomicAdd(&stats[c0 + 16], ss1);
        atomicAdd(&stats[128 + c0], sq0);  atomicAdd(&stats[128 + c0 + 16], sq1);
    }
}

// ---------- streaming segmented aggregate: R[n] = sum relu(bn(x_p)) --------
__global__ __launch_bounds__(256, 8) void k_agg(
    const unsigned short* __restrict__ x, const float* __restrict__ st,
    const int* __restrict__ offs, const int* __restrict__ deg,
    float* __restrict__ R, int NN) {
    int lane = threadIdx.x & 63, w = threadIdx.x >> 6;
    int n = blockIdx.x * 4 + w;
    if (n >= NN) return;
    int c = lane * 2;
    float s0 = st[c], s1 = st[c + 1], t0 = st[128 + c], t1 = st[128 + c + 1];
    int end = offs[n], i = end - deg[n];
    float a0 = 0.f, a1 = 0.f;
    for (; i + 1 < end; i += 2) {
        unsigned v0 = *(const unsigned*)(x + (size_t)i * DIMH + c);
        unsigned v1 = *(const unsigned*)(x + (size_t)(i + 1) * DIMH + c);
        a0 += fmaxf(__uint_as_float(v0 << 16) * s0 + t0, 0.f);
        a1 += fmaxf(__uint_as_float(v0 & 0xffff0000u) * s1 + t1, 0.f);
        a0 += fmaxf(__uint_as_float(v1 << 16) * s0 + t0, 0.f);
        a1 += fmaxf(__uint_as_float(v1 & 0xffff0000u) * s1 + t1, 0.f);
    }
    if (i < end) {
        unsigned v0 = *(const unsigned*)(x + (size_t)i * DIMH + c);
        a0 += fmaxf(__uint_as_float(v0 << 16) * s0 + t0, 0.f);
        a1 += fmaxf(__uint_as_float(v0 & 0xffff0000u) * s1 + t1, 0.f);
    }
    *(float2*)(R + (size_t)n * DIMH + c) = make_float2(a0, a1);
}

// ---------- node GEMM1 ----------
__global__ __launch_bounds__(256, 3) void k_upd1(
    const unsigned short* __restrict__ hb, const float* __restrict__ R,
    const unsigned short* __restrict__ W3c, const float* __restrict__ b3,
    const int* __restrict__ deg, const float* __restrict__ cvec,
    unsigned short* __restrict__ ypre, float* __restrict__ stats, int NN) {
    __shared__ unsigned short A[64 * K3];
    int tid = threadIdx.x, lane = tid & 63, w = tid >> 6;
    int n0 = blockIdx.x * 64;

    bf16x8 bfr[8][2];
    {
        int n = (w << 5) + (lane & 15), kb = (lane >> 4) << 3;
#pragma unroll
        for (int nt = 0; nt < 2; ++nt) {
            const unsigned short* p = W3c + (size_t)(n + nt * 16) * K3 + kb;
#pragma unroll
            for (int ks = 0; ks < 8; ++ks) bfr[ks][nt] = *(const bf16x8*)(p + ks * 32);
        }
    }
    {
        int c16 = tid & 15, r2 = tid >> 4;
#pragma unroll
        for (int rr = 0; rr < 4; ++rr) {
            int row = rr * 16 + r2;
            int node = n0 + row;
            bf16x8 vh = {};
            union { bf16x8 v8; unsigned short s8[8]; } ur;
            if (node < NN) {
                vh = *(const bf16x8*)(hb + (size_t)node * DIMH + c16 * 8);
                float4 r0 = *(const float4*)(R + (size_t)node * DIMH + c16 * 8);
                float4 r1 = *(const float4*)(R + (size_t)node * DIMH + c16 * 8 + 4);
                ur.s8[0] = f2bf(r0.x); ur.s8[1] = f2bf(r0.y); ur.s8[2] = f2bf(r0.z); ur.s8[3] = f2bf(r0.w);
                ur.s8[4] = f2bf(r1.x); ur.s8[5] = f2bf(r1.y); ur.s8[6] = f2bf(r1.z); ur.s8[7] = f2bf(r1.w);
            } else {
#pragma unroll
                for (int j = 0; j < 8; ++j) ur.s8[j] = 0;
            }
            int base = row * K3, sw = (row & 7) << 3;
            *(bf16x8*)&A[(base + c16 * 8) ^ sw] = vh;
            *(bf16x8*)&A[(base + 128 + c16 * 8) ^ sw] = ur.v8;
        }
    }
    __syncthreads();

    f32x4 acc[4][2] = {};
#pragma unroll
    for (int rg = 0; rg < 4; ++rg) {
        int arow = rg * 16 + (lane & 15);
        int base = arow * K3, sw = (arow & 7) << 3, kb = (lane >> 4) << 3;
#pragma unroll
        for (int ks = 0; ks < 8; ++ks) {
            bf16x8 af = *(const bf16x8*)&A[(base + ks * 32 + kb) ^ sw];
            acc[rg][0] = MFMA(af, bfr[ks][0], acc[rg][0]);
            acc[rg][1] = MFMA(af, bfr[ks][1], acc[rg][1]);
        }
    }
    int c0 = (w << 5) + (lane & 15);
    float bias0 = b3[c0], bias1 = b3[c0 + 16];
    float cv0 = cvec[c0], cv1 = cvec[c0 + 16];
    float ss[2] = {0.f, 0.f}, sq[2] = {0.f, 0.f};
#pragma unroll
    for (int rg = 0; rg < 4; ++rg)
#pragma unroll
        for (int r = 0; r < 4; ++r) {
            int node = n0 + rg * 16 + ((lane >> 4) << 2) + r;
            if (node < NN) {
                float dg = (float)deg[node];
                float v0 = acc[rg][0][r] + bias0 + dg * cv0;
                float v1 = acc[rg][1][r] + bias1 + dg * cv1;
                ss[0] += v0; sq[0] += v0 * v0;
                ss[1] += v1; sq[1] += v1 * v1;
                ypre[(size_t)node * DIMH + c0] = f2bf(v0);
                ypre[(size_t)node * DIMH + c0 + 16] = f2bf(v1);
            }
        }
#pragma unroll
    for (int nt = 0; nt < 2; ++nt) {
        ss[nt] += __shfl_xor(ss[nt], 16); ss[nt] += __shfl_xor(ss[nt], 32);
        sq[nt] += __shfl_xor(sq[nt], 16); sq[nt] += __shfl_xor(sq[nt], 32);
    }
    if (lane < 16) {
        atomicAdd(&stats[c0], ss[0]);        atomicAdd(&stats[c0 + 16], ss[1]);
        atomicAdd(&stats[128 + c0], sq[0]);  atomicAdd(&stats[128 + c0 + 16], sq[1]);
    }
}

// ---------- node GEMM2 + residual + LayerNorm ----------
__global__ __launch_bounds__(256, 2) void k_upd2(
    const unsigned short* __restrict__ ypre, const unsigned short* __restrict__ W4t,
    const float* __restrict__ b4, const float* __restrict__ st,
    const float* __restrict__ h, const float* __restrict__ lng,
    const float* __restrict__ lnb, float* __restrict__ out, int NN) {
    const int LDA = 136;
    __shared__ unsigned short A[64 * 136];
    __shared__ float sS[128], sT[128];
    __shared__ float rsum[64], rsq[64];
    int tid = threadIdx.x, lane = tid & 63, w = tid >> 6;
    int n0 = blockIdx.x * 64;
    if (tid < 128) { sS[tid] = st[tid]; sT[tid] = st[128 + tid]; }
    if (tid < 64) { rsum[tid] = 0.f; rsq[tid] = 0.f; }

    bf16x8 bfr[4][2];
    {
        int n = (w << 5) + (lane & 15), kb = (lane >> 4) << 3;
#pragma unroll
        for (int nt = 0; nt < 2; ++nt) {
            const unsigned short* p = W4t + (size_t)(n + nt * 16) * 128 + kb;
#pragma unroll
            for (int ks = 0; ks < 4; ++ks) bfr[ks][nt] = *(const bf16x8*)(p + ks * 32);
        }
    }
    __syncthreads();
    {
        int c16 = tid & 15, r2 = tid >> 4;
#pragma unroll
        for (int rr = 0; rr < 4; ++rr) {
            int row = rr * 16 + r2;
            int node = n0 + row;
            union { bf16x8 v8; unsigned short s[8]; } u;
            if (node < NN) {
                bf16x8 v = *(const bf16x8*)(ypre + (size_t)node * DIMH + c16 * 8);
#pragma unroll
                for (int j = 0; j < 8; ++j) {
                    int c = c16 * 8 + j;
                    union { unsigned uu; float f; } cvt; cvt.uu = ((unsigned)(unsigned short)v[j]) << 16;
                    float f = cvt.f * sS[c] + sT[c];
                    u.s[j] = f2bf(fmaxf(f, 0.f));
                }
            } else {
#pragma unroll
                for (int j = 0; j < 8; ++j) u.s[j] = 0;
            }
            *(bf16x8*)&A[row * LDA + c16 * 8] = u.v8;
        }
    }
    __syncthreads();

    f32x4 acc[4][2] = {};
#pragma unroll
    for (int rg = 0; rg < 4; ++rg) {
        int ab = (rg * 16 + (lane & 15)) * LDA + ((lane >> 4) << 3);
#pragma unroll
        for (int ks = 0; ks < 4; ++ks) {
            bf16x8 af = *(const bf16x8*)&A[ab + ks * 32];
            acc[rg][0] = MFMA(af, bfr[ks][0], acc[rg][0]);
            acc[rg][1] = MFMA(af, bfr[ks][1], acc[rg][1]);
        }
    }
    int c0 = (w << 5) + (lane & 15);
    float bias0 = b4[c0], bias1 = b4[c0 + 16];
    float z[4][2][4];
#pragma unroll
    for (int rg = 0; rg < 4; ++rg)
#pragma unroll
        for (int r = 0; r < 4; ++r) {
            int node = n0 + rg * 16 + ((lane >> 4) << 2) + r;
            float h0 = 0.f, h1 = 0.f;
            if (node < NN) {
                h0 = h[(size_t)node * DIMH + c0];
                h1 = h[(size_t)node * DIMH + c0 + 16];
            }
            z[rg][0][r] = acc[rg][0][r] + bias0 + h0;
            z[rg][1][r] = acc[rg][1][r] + bias1 + h1;
        }
#pragma unroll
    for (int rg = 0; rg < 4; ++rg)
#pragma unroll
        for (int r = 0; r < 4; ++r) {
            float ps = z[rg][0][r] + z[rg][1][r];
            float pq = z[rg][0][r] * z[rg][0][r] + z[rg][1][r] * z[rg][1][r];
#pragma unroll
            for (int m = 1; m < 16; m <<= 1) { ps += __shfl_xor(ps, m); pq += __shfl_xor(pq, m); }
            if ((lane & 15) == 0) {
                int row = rg * 16 + ((lane >> 4) << 2) + r;
                atomicAdd(&rsum[row], ps);
                atomicAdd(&rsq[row], pq);
            }
        }
    __syncthreads();
#pragma unroll
    for (int rg = 0; rg < 4; ++rg)
#pragma unroll
        for (int r = 0; r < 4; ++r) {
            int row = rg * 16 + ((lane >> 4) << 2) + r;
            int node = n0 + row;
            if (node < NN) {
                float mean = rsum[row] * (1.f / 128.f);
                float var = rsq[row] * (1.f / 128.f) - mean * mean;
                float rs = rsqrtf(var + EPS);
                float g0 = lng[c0], g1 = lng[c0 + 16];
                float be0 = lnb[c0], be1 = lnb[c0 + 16];
                out[(size_t)node * DIMH + c0] = (z[rg][0][r] - mean) * rs * g0 + be0;
                out[(size_t)node * DIMH + c0 + 16] = (z[rg][1][r] - mean) * rs * g1 + be1;
            }
        }
}

extern "C" void kernel_launch(void* const* d_in, const int* in_sizes, int n_in,
                              void* d_out, int out_size, void* d_ws, size_t ws_size,
                              hipStream_t stream) {
    const float* h   = (const float*)d_in[0];
    const float* ea  = (const float*)d_in[1];
    const float* W1  = (const float*)d_in[2];
    const float* b1  = (const float*)d_in[3];
    const float* g1  = (const float*)d_in[4];
    const float* be1 = (const float*)d_in[5];
    const float* W2  = (const float*)d_in[6];
    const float* b2  = (const float*)d_in[7];
    const float* W3  = (const float*)d_in[8];
    const float* b3  = (const float*)d_in[9];
    const float* g2  = (const float*)d_in[10];
    const float* be2 = (const float*)d_in[11];
    const float* W4  = (const float*)d_in[12];
    const float* b4  = (const float*)d_in[13];
    const float* lng = (const float*)d_in[14];
    const float* lnb = (const float*)d_in[15];
    const int* eidx  = (const int*)d_in[16];
    int NN = in_sizes[0] / DIMH;
    int E  = in_sizes[16] / 2;
    const int* src = eidx;
    const int* dst = eidx + E;

    char* ws = (char*)d_ws;
    size_t o = 0;
    unsigned short* W1t = (unsigned short*)(ws + o); o += 81920;
    unsigned short* W3c = (unsigned short*)(ws + o); o += 65536;
    unsigned short* W4t = (unsigned short*)(ws + o); o += 32768;
    float* cvec   = (float*)(ws + o); o += 512;
    float* stats1 = (float*)(ws + o); o += 1024;
    float* st1    = (float*)(ws + o); o += 1024;
    float* stats2 = (float*)(ws + o); o += 1024;
    float* st2    = (float*)(ws + o); o += 1024;
    int* bsum   = (int*)(ws + o); o += 1024;
    int* bpre   = (int*)(ws + o); o += 1024;
    int* deg    = (int*)(ws + o); o += 200192;
    int* offs   = (int*)(ws + o); o += 200192;
    int* cursor = (int*)(ws + o); o += 200192;
    int4* edge4 = (int4*)(ws + o); o += (size_t)E * 16;
    unsigned short* hb = (unsigned short*)(ws + o); o += (size_t)NN * DIMH * 2;
    float* R = (float*)(ws + o); o += (size_t)NN * DIMH * 4;
    unsigned short* x = (unsigned short*)(ws + o);   // E*128*2
    unsigned short* ypre = x;                        // x dead after k_agg; reuse

    hipMemsetAsync(stats1, 0, 1024, stream);
    hipMemsetAsync(stats2, 0, 1024, stream);
    hipMemsetAsync(deg, 0, (size_t)NN * 4, stream);

    int nb256 = (NN + 255) / 256;
    k_prep_w<<<(K1 * 128 + 255) / 256, 256, 0, stream>>>(W1, W3, W4, W1t, W3c, W4t);
    k_hb<<<(NN * DIMH / 8 + 255) / 256, 256, 0, stream>>>(h, hb, NN * DIMH / 8);
    k_w23<<<64, 256, 0, stream>>>(W2, W3, W3c);
    k_cvec<<<1, 128, 0, stream>>>(b2, W3, cvec);
    k_deg<<<(E + 255) / 256, 256, 0, stream>>>(dst, deg, E);
    k_part<<<nb256, 256, 0, stream>>>(deg, bsum, NN);
    k_scan2<<<1, 256, 0, stream>>>(bsum, bpre, nb256);
    k_off<<<nb256, 256, 0, stream>>>(deg, bpre, offs, cursor, NN);
    k_scatter<<<(E + 255) / 256, 256, 0, stream>>>(src, dst, cursor, edge4, E);

    k_msg1<<<E / 64, 256, 0, stream>>>(hb, ea, edge4, W1t, b1, x, stats1);
    k_bn<<<1, 128, 0, stream>>>(stats1, g1, be1, st1, (float)E);
    k_agg<<<(NN + 3) / 4, 256, 0, stream>>>(x, st1, offs, deg, R, NN);

    int nb = (NN + 63) / 64;
    k_upd1<<<nb, 256, 0, stream>>>(hb, R, W3c, b3, deg, cvec, ypre, stats2, NN);
    k_bn<<<1, 128, 0, stream>>>(stats2, g2, be2, st2, (float)NN);
    k_upd2<<<nb, 256, 0, stream>>>(ypre, W4t, b4, st2, h, lng, lnb, (float*)d_out, NN);
}